// Round 2
// baseline (602.726 us; speedup 1.0000x reference)
//
#include <hip/hip_runtime.h>
#include <hip/hip_bf16.h>

// out = (adj @ (item_emb @ W)) / (rowsum(adj) + eps)
// adj: [16384][32768] f32, item_emb: [32768][64] f32, W: [64][64] f32
// Strategy: precompute P = item_emb@W (bf16, fragment-packed in d_ws), then one
// streaming pass over adj. Each block owns 16 rows; its 4 waves split K into
// quarters (K-split x4 -> 1024 blocks -> 4 blocks/CU for TLP latency hiding).
// Per wave: fp32 load -> deg accum + bf16 convert -> v_mfma_f32_16x16x16_bf16,
// double-buffered 2 chunks deep. Partials combined in LDS at block end.

#define M 16384
#define K 32768
#define NOUT 64
#define EMB 64
#define EPSV 1e-8f
#define KSPLIT 4
#define KQ (K / KSPLIT)      // 8192 cols per wave
#define NC (KQ / 64)         // 128 chunks per wave

typedef __attribute__((ext_vector_type(4))) float f32x4;
typedef __attribute__((ext_vector_type(4))) short s16x4;
typedef __attribute__((ext_vector_type(4))) unsigned short u16x4;
typedef __attribute__((ext_vector_type(8))) unsigned short u16x8;

static __device__ __forceinline__ unsigned short f2bf(float f) {
    // round-to-nearest-even fp32 -> bf16 (inputs finite, no NaN handling)
    unsigned int u = __float_as_uint(f);
    u += 0x7fffu + ((u >> 16) & 1u);
    return (unsigned short)(u >> 16);
}

// ---------------------------------------------------------------------------
// Kernel 1: P = item_emb @ W, stored bf16 in MFMA-B-fragment-packed order.
// granule (16B) index = (kc*8 + nt*2 + kp)*64 + lane; granule holds ksub=2kp
// (bytes 0..7) and ksub=2kp+1 (bytes 8..15), each 4 consecutive-k bf16.
// ---------------------------------------------------------------------------
__global__ __launch_bounds__(256) void pack_p_kernel(const float* __restrict__ emb,
                                                     const float* __restrict__ W,
                                                     unsigned short* __restrict__ ppack) {
    int tid = blockIdx.x * 256 + threadIdx.x;   // 0 .. 524287
    int kq  = tid >> 6;                          // k-quad index (k = 4*kq)
    int n   = tid & 63;

    const f32x4* emb4 = (const f32x4*)(emb + (size_t)(kq * 4) * EMB);
    float acc0 = 0.f, acc1 = 0.f, acc2 = 0.f, acc3 = 0.f;
#pragma unroll
    for (int e4 = 0; e4 < 16; ++e4) {
        float w0 = W[(4 * e4 + 0) * NOUT + n];
        float w1 = W[(4 * e4 + 1) * NOUT + n];
        float w2 = W[(4 * e4 + 2) * NOUT + n];
        float w3 = W[(4 * e4 + 3) * NOUT + n];
        f32x4 e0 = emb4[0 * 16 + e4];
        f32x4 e1 = emb4[1 * 16 + e4];
        f32x4 e2 = emb4[2 * 16 + e4];
        f32x4 e3 = emb4[3 * 16 + e4];
        acc0 += e0.x * w0 + e0.y * w1 + e0.z * w2 + e0.w * w3;
        acc1 += e1.x * w0 + e1.y * w1 + e1.z * w2 + e1.w * w3;
        acc2 += e2.x * w0 + e2.y * w1 + e2.z * w2 + e2.w * w3;
        acc3 += e3.x * w0 + e3.y * w1 + e3.z * w2 + e3.w * w3;
    }

    int kc   = kq >> 4;
    int ksub = (kq >> 2) & 3;
    int g    = kq & 3;
    int nt   = n >> 4;
    int r    = n & 15;
    int lane = g * 16 + r;
    size_t gran = (size_t)(kc * 8 + nt * 2 + (ksub >> 1)) * 64 + lane; // 16B units
    u16x4 v = { f2bf(acc0), f2bf(acc1), f2bf(acc2), f2bf(acc3) };
    *((u16x4*)ppack + gran * 2 + (ksub & 1)) = v;
}

// ---------------------------------------------------------------------------
// Kernel 2: streaming adj pass. Block = 16 rows; wave w = K-quarter w.
// Per K-chunk (64): lane loads 4x float4 of adj (its A fragments), 8x 16B of
// packed P (B fragments), 16 MFMA. 2-deep register double buffer.
// Epilogue: per-wave partials summed in LDS, deg-divide, coalesced store.
// ---------------------------------------------------------------------------
__global__ __launch_bounds__(256, 3) void meanconv_main(const float* __restrict__ adj,
                                                        const unsigned short* __restrict__ ppack,
                                                        float* __restrict__ out) {
    const int lane = threadIdx.x & 63;
    const int w = threadIdx.x >> 6;          // wave index = K-quarter
    const int r = lane & 15;
    const int g = lane >> 4;
    const int row_base = blockIdx.x * 16;

    __shared__ float part[KSPLIT][16 * NOUT];   // 16 KB
    __shared__ float degp[KSPLIT][16];

    const float* arow = adj + (size_t)(row_base + r) * K + (size_t)w * KQ + g * 4;
    const u16x8* bbase = (const u16x8*)ppack + lane + (size_t)(w * NC) * 8 * 64;

    f32x4 acc[4];
#pragma unroll
    for (int t = 0; t < 4; ++t) acc[t] = (f32x4)0.0f;
    float dsum = 0.0f;

    f32x4 aA[4], aB[4];
    u16x8 bA[8], bB[8];

    // prologue: chunks 0 and 1
#pragma unroll
    for (int s = 0; s < 4; ++s)
        aA[s] = __builtin_nontemporal_load((const f32x4*)(arow + 0 * 64 + s * 16));
#pragma unroll
    for (int q = 0; q < 8; ++q) bA[q] = bbase[((size_t)0 * 8 + q) * 64];
#pragma unroll
    for (int s = 0; s < 4; ++s)
        aB[s] = __builtin_nontemporal_load((const f32x4*)(arow + 1 * 64 + s * 16));
#pragma unroll
    for (int q = 0; q < 8; ++q) bB[q] = bbase[((size_t)1 * 8 + q) * 64];

    for (int kc = 0; kc < NC; kc += 2) {
        // ---- compute chunk kc (buffers A) ----
#pragma unroll
        for (int s = 0; s < 4; ++s) {
            f32x4 av = aA[s];
            dsum += av.x + av.y + av.z + av.w;
            s16x4 af = { (short)f2bf(av.x), (short)f2bf(av.y),
                         (short)f2bf(av.z), (short)f2bf(av.w) };
#pragma unroll
            for (int nt = 0; nt < 4; ++nt) {
                u16x8 bb = bA[nt * 2 + (s >> 1)];
                const int h = (s & 1) * 4;
                s16x4 bfq = { (short)bb[h + 0], (short)bb[h + 1],
                              (short)bb[h + 2], (short)bb[h + 3] };
                acc[nt] = __builtin_amdgcn_mfma_f32_16x16x16bf16_1k(af, bfq, acc[nt], 0, 0, 0);
            }
        }
        if (kc + 2 < NC) {
#pragma unroll
            for (int s = 0; s < 4; ++s)
                aA[s] = __builtin_nontemporal_load(
                    (const f32x4*)(arow + (size_t)(kc + 2) * 64 + s * 16));
#pragma unroll
            for (int q = 0; q < 8; ++q) bA[q] = bbase[((size_t)(kc + 2) * 8 + q) * 64];
        }
        // ---- compute chunk kc+1 (buffers B) ----
#pragma unroll
        for (int s = 0; s < 4; ++s) {
            f32x4 av = aB[s];
            dsum += av.x + av.y + av.z + av.w;
            s16x4 af = { (short)f2bf(av.x), (short)f2bf(av.y),
                         (short)f2bf(av.z), (short)f2bf(av.w) };
#pragma unroll
            for (int nt = 0; nt < 4; ++nt) {
                u16x8 bb = bB[nt * 2 + (s >> 1)];
                const int h = (s & 1) * 4;
                s16x4 bfq = { (short)bb[h + 0], (short)bb[h + 1],
                              (short)bb[h + 2], (short)bb[h + 3] };
                acc[nt] = __builtin_amdgcn_mfma_f32_16x16x16bf16_1k(af, bfq, acc[nt], 0, 0, 0);
            }
        }
        if (kc + 3 < NC) {
#pragma unroll
            for (int s = 0; s < 4; ++s)
                aB[s] = __builtin_nontemporal_load(
                    (const f32x4*)(arow + (size_t)(kc + 3) * 64 + s * 16));
#pragma unroll
            for (int q = 0; q < 8; ++q) bB[q] = bbase[((size_t)(kc + 3) * 8 + q) * 64];
        }
    }

    // per-wave deg partial: lane (r,g) holds part of row r; reduce across g.
    float deg = dsum;
    deg += __shfl_xor(deg, 16);
    deg += __shfl_xor(deg, 32);
    if (g == 0) degp[w][r] = deg;

    // write wave's partial acc to LDS in (row,col) order.
    // acc[nt][i] = D[row 4g+i][col nt*16+r]   (verified mapping)
#pragma unroll
    for (int i = 0; i < 4; ++i)
#pragma unroll
        for (int nt = 0; nt < 4; ++nt)
            part[w][(g * 4 + i) * NOUT + nt * 16 + r] = acc[nt][i];

    __syncthreads();

    // 256 threads x 4 contiguous outputs: sum 4 partials, deg-divide, store.
    const int f = threadIdx.x * 4;           // flat index into 16x64 tile
    const int orow = f >> 6;                  // row within block (f 4-aligned)
    f32x4 s0 = *(const f32x4*)&part[0][f];
    f32x4 s1 = *(const f32x4*)&part[1][f];
    f32x4 s2 = *(const f32x4*)&part[2][f];
    f32x4 s3 = *(const f32x4*)&part[3][f];
    f32x4 ssum = (s0 + s1) + (s2 + s3);
    float degf = ((degp[0][orow] + degp[1][orow]) + (degp[2][orow] + degp[3][orow]));
    float rd = 1.0f / (degf + EPSV);
    ssum *= rd;
    *(f32x4*)(out + (size_t)row_base * NOUT + f) = ssum;
}

extern "C" void kernel_launch(void* const* d_in, const int* in_sizes, int n_in,
                              void* d_out, int out_size, void* d_ws, size_t ws_size,
                              hipStream_t stream) {
    const float* adj = (const float*)d_in[0];
    const float* emb = (const float*)d_in[1];
    const float* W   = (const float*)d_in[2];
    float* out = (float*)d_out;
    unsigned short* ppack = (unsigned short*)d_ws;  // 4 MB bf16 packed P

    hipLaunchKernelGGL(pack_p_kernel, dim3((K / 4 * NOUT) / 256), dim3(256), 0, stream,
                       emb, W, ppack);
    hipLaunchKernelGGL(meanconv_main, dim3(M / 16), dim3(256), 0, stream,
                       adj, ppack, out);
}

// Round 3
// 375.139 us; speedup vs baseline: 1.6067x; 1.6067x over previous
//
#include <hip/hip_runtime.h>
#include <hip/hip_bf16.h>

// out = (adj @ (item_emb @ W)) / (rowsum(adj) + eps)
// adj: [16384][32768] f32, item_emb: [32768][64] f32, W: [64][64] f32
// v3: canonical LDS-staged streaming pass.
//  - P = item_emb@W precomputed bf16, MFMA-fragment-packed (verified layout).
//  - Block = 64 rows, grid 256 (1/CU). K-superchunk = 128 floats.
//  - A staged global->LDS via global_load_lds (16B/lane, 512B-contiguous rows),
//    XOR-swizzled on the GLOBAL source (dest must be linear), read swizzled.
//  - B staged to LDS once per block, shared by all 4 waves (TD traffic /4).
//  - 3-buffer pipeline, counted s_waitcnt vmcnt(12) (never drain to 0 mid-loop).

#define M 16384
#define K 32768
#define NOUT 64
#define EMB 64
#define EPSV 1e-8f
#define SCF 128                    // superchunk: floats per row
#define NSC (K / SCF)              // 256 iterations
#define BROWS 64                   // rows per block
#define ABUF 32768                 // 64 rows * 512 B
#define BBUF 16384                 // 128k * 64n * 2 B
#define BUFSZ (ABUF + BBUF)

typedef __attribute__((ext_vector_type(4))) float f32x4;
typedef __attribute__((ext_vector_type(4))) short s16x4;
typedef __attribute__((ext_vector_type(4))) unsigned short u16x4;
typedef __attribute__((ext_vector_type(8))) unsigned short u16x8;

static __device__ __forceinline__ unsigned short f2bf(float f) {
    // round-to-nearest-even fp32 -> bf16 (inputs finite)
    unsigned int u = __float_as_uint(f);
    u += 0x7fffu + ((u >> 16) & 1u);
    return (unsigned short)(u >> 16);
}

static __device__ __forceinline__ void gl_lds16(const void* g, void* l) {
    // async global->LDS, 16 B per lane; LDS dest = wave-uniform base + lane*16
    __builtin_amdgcn_global_load_lds(
        (const __attribute__((address_space(1))) unsigned int*)g,
        (__attribute__((address_space(3))) unsigned int*)l, 16, 0, 0);
}

static __device__ __forceinline__ s16x4 lo4(u16x8 v) {
    s16x4 t = {(short)v[0], (short)v[1], (short)v[2], (short)v[3]};
    return t;
}
static __device__ __forceinline__ s16x4 hi4(u16x8 v) {
    s16x4 t = {(short)v[4], (short)v[5], (short)v[6], (short)v[7]};
    return t;
}

// ---------------------------------------------------------------------------
// Kernel 1: P = item_emb @ W, bf16, MFMA-B-fragment-packed (verified, as R1).
// granule (16B) index = (kc*8 + nt*2 + kp)*64 + lane; holds ksub=2kp (lo 8B)
// and ksub=2kp+1 (hi 8B), each 4 consecutive-k bf16.
// ---------------------------------------------------------------------------
__global__ __launch_bounds__(256) void pack_p_kernel(const float* __restrict__ emb,
                                                     const float* __restrict__ W,
                                                     unsigned short* __restrict__ ppack) {
    int tid = blockIdx.x * 256 + threadIdx.x;
    int kq  = tid >> 6;
    int n   = tid & 63;

    const f32x4* emb4 = (const f32x4*)(emb + (size_t)(kq * 4) * EMB);
    float acc0 = 0.f, acc1 = 0.f, acc2 = 0.f, acc3 = 0.f;
#pragma unroll
    for (int e4 = 0; e4 < 16; ++e4) {
        float w0 = W[(4 * e4 + 0) * NOUT + n];
        float w1 = W[(4 * e4 + 1) * NOUT + n];
        float w2 = W[(4 * e4 + 2) * NOUT + n];
        float w3 = W[(4 * e4 + 3) * NOUT + n];
        f32x4 e0 = emb4[0 * 16 + e4];
        f32x4 e1 = emb4[1 * 16 + e4];
        f32x4 e2 = emb4[2 * 16 + e4];
        f32x4 e3 = emb4[3 * 16 + e4];
        acc0 += e0.x * w0 + e0.y * w1 + e0.z * w2 + e0.w * w3;
        acc1 += e1.x * w0 + e1.y * w1 + e1.z * w2 + e1.w * w3;
        acc2 += e2.x * w0 + e2.y * w1 + e2.z * w2 + e2.w * w3;
        acc3 += e3.x * w0 + e3.y * w1 + e3.z * w2 + e3.w * w3;
    }

    int kc   = kq >> 4;
    int ksub = (kq >> 2) & 3;
    int g    = kq & 3;
    int nt   = n >> 4;
    int r    = n & 15;
    int lane = g * 16 + r;
    size_t gran = (size_t)(kc * 8 + nt * 2 + (ksub >> 1)) * 64 + lane;
    u16x4 v = { f2bf(acc0), f2bf(acc1), f2bf(acc2), f2bf(acc3) };
    *((u16x4*)ppack + gran * 2 + (ksub & 1)) = v;
}

// ---------------------------------------------------------------------------
// Kernel 2: streaming adj pass, LDS-staged, 3-buffer counted-vmcnt pipeline.
// ---------------------------------------------------------------------------
__global__ __launch_bounds__(256) void meanconv_main(const float* __restrict__ adj,
                                                     const unsigned short* __restrict__ ppack,
                                                     float* __restrict__ out) {
    __shared__ __align__(1024) unsigned char smem[3 * BUFSZ];   // 144 KB

    const int tid  = threadIdx.x;
    const int lane = tid & 63;
    const int w    = tid >> 6;        // wave 0..3, owns rows w*16..w*16+15
    const int r    = lane & 15;
    const int g    = lane >> 4;
    const int h    = lane >> 5;       // staging: row half within call
    const int l31  = lane & 31;
    const int row_base = blockIdx.x * BROWS;

    const char* adjB = (const char*)adj;

    // ---- staging (12 x global_load_lds per wave per superchunk) ----
    auto STAGE = [&](int sc, int buf) {
        unsigned char* abase = smem + buf * BUFSZ;
        unsigned char* bbase = abase + ABUF;
        // A: 8 calls, each stages 2 rows x 512 B (contiguous per row).
#pragma unroll
        for (int c = 0; c < 8; ++c) {
            const int lrow = w * 16 + c * 2 + h;     // local row 0..63
            const char* src = adjB
                + ((size_t)(row_base + lrow) * K + (size_t)sc * SCF) * 4
                + ((l31 * 16) ^ ((lrow & 7) << 4));  // pre-swizzled source
            void* dst = abase + (size_t)(w * 16 + c * 2) * 512;  // wave-uniform
            gl_lds16(src, dst);
        }
        // B: 4 calls, linear 16 KB superchunk slice (L2/L3-resident).
#pragma unroll
        for (int c2 = 0; c2 < 4; ++c2) {
            const char* src = (const char*)ppack + (size_t)sc * BBUF
                              + w * 4096 + c2 * 1024 + lane * 16;
            void* dst = bbase + w * 4096 + c2 * 1024;
            gl_lds16(src, dst);
        }
    };

    f32x4 acc[4];
#pragma unroll
    for (int t = 0; t < 4; ++t) acc[t] = (f32x4)0.0f;
    float dsum = 0.0f;

    const int swz = (r & 7) << 4;

    STAGE(0, 0);
    STAGE(1, 1);

    int buf = 0;
    for (int sc = 0; sc < NSC; ++sc) {
        if (sc + 1 < NSC) {
            asm volatile("s_waitcnt vmcnt(12)" ::: "memory");  // stage(sc) done,
        } else {                                               // stage(sc+1) in flight
            asm volatile("s_waitcnt vmcnt(0)" ::: "memory");   // tail: drain
        }
        asm volatile("s_waitcnt lgkmcnt(0)" ::: "memory");
        __builtin_amdgcn_s_barrier();

        {   // prefetch 2 ahead, into the buffer last read at iter sc-1
            int nbuf = buf + 2; if (nbuf >= 3) nbuf -= 3;
            if (sc + 2 < NSC) STAGE(sc + 2, nbuf);
        }

        // ---- compute superchunk sc from buf ----
        {
            unsigned char* abase = smem + buf * BUFSZ;
            unsigned char* bbase = abase + ABUF;
            const unsigned char* arow_l = abase + (size_t)(w * 16 + r) * 512;
            const unsigned char* blane  = bbase + lane * 16;
#pragma unroll
            for (int d = 0; d < 2; ++d) {
#pragma unroll
                for (int kp = 0; kp < 2; ++kp) {
                    const int j0 = d * 4 + kp * 2;
                    f32x4 a0 = *(const f32x4*)(arow_l + (((j0 + 0) * 64 + g * 16) ^ swz));
                    f32x4 a1 = *(const f32x4*)(arow_l + (((j0 + 1) * 64 + g * 16) ^ swz));
                    u16x8 b0 = *(const u16x8*)(blane + (size_t)(d * 8 + 0 * 2 + kp) * 1024);
                    u16x8 b1 = *(const u16x8*)(blane + (size_t)(d * 8 + 1 * 2 + kp) * 1024);
                    u16x8 b2 = *(const u16x8*)(blane + (size_t)(d * 8 + 2 * 2 + kp) * 1024);
                    u16x8 b3 = *(const u16x8*)(blane + (size_t)(d * 8 + 3 * 2 + kp) * 1024);
                    dsum += a0.x + a0.y + a0.z + a0.w;
                    dsum += a1.x + a1.y + a1.z + a1.w;
                    s16x4 af0 = { (short)f2bf(a0.x), (short)f2bf(a0.y),
                                  (short)f2bf(a0.z), (short)f2bf(a0.w) };
                    s16x4 af1 = { (short)f2bf(a1.x), (short)f2bf(a1.y),
                                  (short)f2bf(a1.z), (short)f2bf(a1.w) };
                    acc[0] = __builtin_amdgcn_mfma_f32_16x16x16bf16_1k(af0, lo4(b0), acc[0], 0, 0, 0);
                    acc[0] = __builtin_amdgcn_mfma_f32_16x16x16bf16_1k(af1, hi4(b0), acc[0], 0, 0, 0);
                    acc[1] = __builtin_amdgcn_mfma_f32_16x16x16bf16_1k(af0, lo4(b1), acc[1], 0, 0, 0);
                    acc[1] = __builtin_amdgcn_mfma_f32_16x16x16bf16_1k(af1, hi4(b1), acc[1], 0, 0, 0);
                    acc[2] = __builtin_amdgcn_mfma_f32_16x16x16bf16_1k(af0, lo4(b2), acc[2], 0, 0, 0);
                    acc[2] = __builtin_amdgcn_mfma_f32_16x16x16bf16_1k(af1, hi4(b2), acc[2], 0, 0, 0);
                    acc[3] = __builtin_amdgcn_mfma_f32_16x16x16bf16_1k(af0, lo4(b3), acc[3], 0, 0, 0);
                    acc[3] = __builtin_amdgcn_mfma_f32_16x16x16bf16_1k(af1, hi4(b3), acc[3], 0, 0, 0);
                }
            }
        }
        buf += 1; if (buf >= 3) buf -= 3;
    }

    // ---- epilogue (verified R1 mapping) ----
    // lane (r,g) summed LDS row (w*16+r) over its g-quarter -> reduce over g.
    float deg = dsum;
    deg += __shfl_xor(deg, 16);
    deg += __shfl_xor(deg, 32);
    // acc[nt][i] = D[row 4g+i][col nt*16+r] within wave tile.
    float* orow = out + (size_t)(row_base + w * 16) * NOUT + r;
#pragma unroll
    for (int i = 0; i < 4; ++i) {
        float dgi = __shfl(deg, g * 4 + i);
        float rd = 1.0f / (dgi + EPSV);
#pragma unroll
        for (int nt = 0; nt < 4; ++nt) {
            orow[(g * 4 + i) * NOUT + nt * 16] = acc[nt][i] * rd;
        }
    }
}

extern "C" void kernel_launch(void* const* d_in, const int* in_sizes, int n_in,
                              void* d_out, int out_size, void* d_ws, size_t ws_size,
                              hipStream_t stream) {
    const float* adj = (const float*)d_in[0];
    const float* emb = (const float*)d_in[1];
    const float* W   = (const float*)d_in[2];
    float* out = (float*)d_out;
    unsigned short* ppack = (unsigned short*)d_ws;  // 4 MB bf16 packed P

    hipLaunchKernelGGL(pack_p_kernel, dim3((K / 4 * NOUT) / 256), dim3(256), 0, stream,
                       emb, W, ppack);
    hipLaunchKernelGGL(meanconv_main, dim3(M / BROWS), dim3(256), 0, stream,
                       adj, ppack, out);
}

// Round 4
// 346.649 us; speedup vs baseline: 1.7387x; 1.0822x over previous
//
#include <hip/hip_runtime.h>
#include <hip/hip_bf16.h>

// out = (adj @ (item_emb @ W)) / (rowsum(adj) + eps)
// adj: [16384][32768] f32, item_emb: [32768][64] f32, W: [64][64] f32
// v4 = v3 + non-temporal (CPol NT, aux=2) on adj staging loads so the 2 GB
// read-once stream doesn't evict the reused B panel from L2.
//  - P = item_emb@W precomputed bf16, MFMA-fragment-packed (verified layout).
//  - Block = 64 rows, grid 256 (1/CU). K-superchunk = 128 floats.
//  - A staged global->LDS via global_load_lds (16B/lane, 512B-contiguous rows),
//    XOR-swizzled on the GLOBAL source (dest must be linear), read swizzled.
//  - B staged to LDS once per block, shared by all 4 waves.
//  - 3-buffer pipeline, counted s_waitcnt vmcnt(12) (never drain to 0 mid-loop).

#define M 16384
#define K 32768
#define NOUT 64
#define EMB 64
#define EPSV 1e-8f
#define SCF 128                    // superchunk: floats per row
#define NSC (K / SCF)              // 256 iterations
#define BROWS 64                   // rows per block
#define ABUF 32768                 // 64 rows * 512 B
#define BBUF 16384                 // 128k * 64n * 2 B
#define BUFSZ (ABUF + BBUF)

typedef __attribute__((ext_vector_type(4))) float f32x4;
typedef __attribute__((ext_vector_type(4))) short s16x4;
typedef __attribute__((ext_vector_type(4))) unsigned short u16x4;
typedef __attribute__((ext_vector_type(8))) unsigned short u16x8;

static __device__ __forceinline__ unsigned short f2bf(float f) {
    // round-to-nearest-even fp32 -> bf16 (inputs finite)
    unsigned int u = __float_as_uint(f);
    u += 0x7fffu + ((u >> 16) & 1u);
    return (unsigned short)(u >> 16);
}

static __device__ __forceinline__ void gl_lds16_nt(const void* g, void* l) {
    // async global->LDS, 16 B/lane, CPol NT (bit1): non-temporal stream
    __builtin_amdgcn_global_load_lds(
        (const __attribute__((address_space(1))) unsigned int*)g,
        (__attribute__((address_space(3))) unsigned int*)l, 16, 0, 2);
}

static __device__ __forceinline__ void gl_lds16(const void* g, void* l) {
    // async global->LDS, 16 B/lane, default cache policy (B panel: keep in L2)
    __builtin_amdgcn_global_load_lds(
        (const __attribute__((address_space(1))) unsigned int*)g,
        (__attribute__((address_space(3))) unsigned int*)l, 16, 0, 0);
}

static __device__ __forceinline__ s16x4 lo4(u16x8 v) {
    s16x4 t = {(short)v[0], (short)v[1], (short)v[2], (short)v[3]};
    return t;
}
static __device__ __forceinline__ s16x4 hi4(u16x8 v) {
    s16x4 t = {(short)v[4], (short)v[5], (short)v[6], (short)v[7]};
    return t;
}

// ---------------------------------------------------------------------------
// Kernel 1: P = item_emb @ W, bf16, MFMA-B-fragment-packed (verified, as R1).
// granule (16B) index = (kc*8 + nt*2 + kp)*64 + lane; holds ksub=2kp (lo 8B)
// and ksub=2kp+1 (hi 8B), each 4 consecutive-k bf16.
// ---------------------------------------------------------------------------
__global__ __launch_bounds__(256) void pack_p_kernel(const float* __restrict__ emb,
                                                     const float* __restrict__ W,
                                                     unsigned short* __restrict__ ppack) {
    int tid = blockIdx.x * 256 + threadIdx.x;
    int kq  = tid >> 6;
    int n   = tid & 63;

    const f32x4* emb4 = (const f32x4*)(emb + (size_t)(kq * 4) * EMB);
    float acc0 = 0.f, acc1 = 0.f, acc2 = 0.f, acc3 = 0.f;
#pragma unroll
    for (int e4 = 0; e4 < 16; ++e4) {
        float w0 = W[(4 * e4 + 0) * NOUT + n];
        float w1 = W[(4 * e4 + 1) * NOUT + n];
        float w2 = W[(4 * e4 + 2) * NOUT + n];
        float w3 = W[(4 * e4 + 3) * NOUT + n];
        f32x4 e0 = emb4[0 * 16 + e4];
        f32x4 e1 = emb4[1 * 16 + e4];
        f32x4 e2 = emb4[2 * 16 + e4];
        f32x4 e3 = emb4[3 * 16 + e4];
        acc0 += e0.x * w0 + e0.y * w1 + e0.z * w2 + e0.w * w3;
        acc1 += e1.x * w0 + e1.y * w1 + e1.z * w2 + e1.w * w3;
        acc2 += e2.x * w0 + e2.y * w1 + e2.z * w2 + e2.w * w3;
        acc3 += e3.x * w0 + e3.y * w1 + e3.z * w2 + e3.w * w3;
    }

    int kc   = kq >> 4;
    int ksub = (kq >> 2) & 3;
    int g    = kq & 3;
    int nt   = n >> 4;
    int r    = n & 15;
    int lane = g * 16 + r;
    size_t gran = (size_t)(kc * 8 + nt * 2 + (ksub >> 1)) * 64 + lane;
    u16x4 v = { f2bf(acc0), f2bf(acc1), f2bf(acc2), f2bf(acc3) };
    *((u16x4*)ppack + gran * 2 + (ksub & 1)) = v;
}

// ---------------------------------------------------------------------------
// Kernel 2: streaming adj pass, LDS-staged, 3-buffer counted-vmcnt pipeline.
// ---------------------------------------------------------------------------
__global__ __launch_bounds__(256) void meanconv_main(const float* __restrict__ adj,
                                                     const unsigned short* __restrict__ ppack,
                                                     float* __restrict__ out) {
    __shared__ __align__(1024) unsigned char smem[3 * BUFSZ];   // 144 KB

    const int tid  = threadIdx.x;
    const int lane = tid & 63;
    const int w    = tid >> 6;        // wave 0..3, owns rows w*16..w*16+15
    const int r    = lane & 15;
    const int g    = lane >> 4;
    const int h    = lane >> 5;       // staging: row half within call
    const int l31  = lane & 31;
    const int row_base = blockIdx.x * BROWS;

    const char* adjB = (const char*)adj;

    // ---- staging (12 x global_load_lds per wave per superchunk) ----
    auto STAGE = [&](int sc, int buf) {
        unsigned char* abase = smem + buf * BUFSZ;
        unsigned char* bbase = abase + ABUF;
        // A: 8 calls, each stages 2 rows x 512 B (contiguous per row). NT.
#pragma unroll
        for (int c = 0; c < 8; ++c) {
            const int lrow = w * 16 + c * 2 + h;     // local row 0..63
            const char* src = adjB
                + ((size_t)(row_base + lrow) * K + (size_t)sc * SCF) * 4
                + ((l31 * 16) ^ ((lrow & 7) << 4));  // pre-swizzled source
            void* dst = abase + (size_t)(w * 16 + c * 2) * 512;  // wave-uniform
            gl_lds16_nt(src, dst);
        }
        // B: 4 calls, linear 16 KB superchunk slice (L2/L3-resident, cached).
#pragma unroll
        for (int c2 = 0; c2 < 4; ++c2) {
            const char* src = (const char*)ppack + (size_t)sc * BBUF
                              + w * 4096 + c2 * 1024 + lane * 16;
            void* dst = bbase + w * 4096 + c2 * 1024;
            gl_lds16(src, dst);
        }
    };

    f32x4 acc[4];
#pragma unroll
    for (int t = 0; t < 4; ++t) acc[t] = (f32x4)0.0f;
    float dsum = 0.0f;

    const int swz = (r & 7) << 4;

    STAGE(0, 0);
    STAGE(1, 1);

    int buf = 0;
    for (int sc = 0; sc < NSC; ++sc) {
        if (sc + 1 < NSC) {
            asm volatile("s_waitcnt vmcnt(12)" ::: "memory");  // stage(sc) done,
        } else {                                               // stage(sc+1) in flight
            asm volatile("s_waitcnt vmcnt(0)" ::: "memory");   // tail: drain
        }
        asm volatile("s_waitcnt lgkmcnt(0)" ::: "memory");
        __builtin_amdgcn_s_barrier();

        {   // prefetch 2 ahead, into the buffer last read at iter sc-1
            int nbuf = buf + 2; if (nbuf >= 3) nbuf -= 3;
            if (sc + 2 < NSC) STAGE(sc + 2, nbuf);
        }

        // ---- compute superchunk sc from buf ----
        {
            unsigned char* abase = smem + buf * BUFSZ;
            unsigned char* bbase = abase + ABUF;
            const unsigned char* arow_l = abase + (size_t)(w * 16 + r) * 512;
            const unsigned char* blane  = bbase + lane * 16;
#pragma unroll
            for (int d = 0; d < 2; ++d) {
#pragma unroll
                for (int kp = 0; kp < 2; ++kp) {
                    const int j0 = d * 4 + kp * 2;
                    f32x4 a0 = *(const f32x4*)(arow_l + (((j0 + 0) * 64 + g * 16) ^ swz));
                    f32x4 a1 = *(const f32x4*)(arow_l + (((j0 + 1) * 64 + g * 16) ^ swz));
                    u16x8 b0 = *(const u16x8*)(blane + (size_t)(d * 8 + 0 * 2 + kp) * 1024);
                    u16x8 b1 = *(const u16x8*)(blane + (size_t)(d * 8 + 1 * 2 + kp) * 1024);
                    u16x8 b2 = *(const u16x8*)(blane + (size_t)(d * 8 + 2 * 2 + kp) * 1024);
                    u16x8 b3 = *(const u16x8*)(blane + (size_t)(d * 8 + 3 * 2 + kp) * 1024);
                    dsum += a0.x + a0.y + a0.z + a0.w;
                    dsum += a1.x + a1.y + a1.z + a1.w;
                    s16x4 af0 = { (short)f2bf(a0.x), (short)f2bf(a0.y),
                                  (short)f2bf(a0.z), (short)f2bf(a0.w) };
                    s16x4 af1 = { (short)f2bf(a1.x), (short)f2bf(a1.y),
                                  (short)f2bf(a1.z), (short)f2bf(a1.w) };
                    acc[0] = __builtin_amdgcn_mfma_f32_16x16x16bf16_1k(af0, lo4(b0), acc[0], 0, 0, 0);
                    acc[0] = __builtin_amdgcn_mfma_f32_16x16x16bf16_1k(af1, hi4(b0), acc[0], 0, 0, 0);
                    acc[1] = __builtin_amdgcn_mfma_f32_16x16x16bf16_1k(af0, lo4(b1), acc[1], 0, 0, 0);
                    acc[1] = __builtin_amdgcn_mfma_f32_16x16x16bf16_1k(af1, hi4(b1), acc[1], 0, 0, 0);
                    acc[2] = __builtin_amdgcn_mfma_f32_16x16x16bf16_1k(af0, lo4(b2), acc[2], 0, 0, 0);
                    acc[2] = __builtin_amdgcn_mfma_f32_16x16x16bf16_1k(af1, hi4(b2), acc[2], 0, 0, 0);
                    acc[3] = __builtin_amdgcn_mfma_f32_16x16x16bf16_1k(af0, lo4(b3), acc[3], 0, 0, 0);
                    acc[3] = __builtin_amdgcn_mfma_f32_16x16x16bf16_1k(af1, hi4(b3), acc[3], 0, 0, 0);
                }
            }
        }
        buf += 1; if (buf >= 3) buf -= 3;
    }

    // ---- epilogue (verified R1 mapping) ----
    // lane (r,g) summed row (w*16+r) over its g-quarter -> reduce over g.
    float deg = dsum;
    deg += __shfl_xor(deg, 16);
    deg += __shfl_xor(deg, 32);
    // acc[nt][i] = D[row 4g+i][col nt*16+r] within wave tile.
    float* orow = out + (size_t)(row_base + w * 16) * NOUT + r;
#pragma unroll
    for (int i = 0; i < 4; ++i) {
        float dgi = __shfl(deg, g * 4 + i);
        float rd = 1.0f / (dgi + EPSV);
#pragma unroll
        for (int nt = 0; nt < 4; ++nt) {
            orow[(g * 4 + i) * NOUT + nt * 16] = acc[nt][i] * rd;
        }
    }
}

extern "C" void kernel_launch(void* const* d_in, const int* in_sizes, int n_in,
                              void* d_out, int out_size, void* d_ws, size_t ws_size,
                              hipStream_t stream) {
    const float* adj = (const float*)d_in[0];
    const float* emb = (const float*)d_in[1];
    const float* W   = (const float*)d_in[2];
    float* out = (float*)d_out;
    unsigned short* ppack = (unsigned short*)d_ws;  // 4 MB bf16 packed P

    hipLaunchKernelGGL(pack_p_kernel, dim3((K / 4 * NOUT) / 256), dim3(256), 0, stream,
                       emb, W, ppack);
    hipLaunchKernelGGL(meanconv_main, dim3(M / BROWS), dim3(256), 0, stream,
                       adj, ppack, out);
}